// Round 2
// baseline (1021.189 us; speedup 1.0000x reference)
//
#include <hip/hip_runtime.h>
#include <math.h>

#define HW 12544      // 112*112
#define HW4 3136      // HW/4
#define W_IMG 112
#define B_SZ 2
#define TO 16         // output channels per thread in conv kernel

// ---------------------------------------------------------------------------
// Generic 1x1 conv: out[b, o, hw] = sum_c w[o,c] * in[b*in_bstride + c*HW + hw]
// Epilogue modes: 0 = none, 1 = *scale, 2 = tanh(v)+res, 3 = (tanh(v)+res)*mul
// Block: 256 threads, each thread computes TO output channels x 4 pixels.
// Grid: (ceil(HW4/256)=13, ceil(O/TO), B)
// ---------------------------------------------------------------------------
__global__ __launch_bounds__(256) void conv1x1_k(
    const float* __restrict__ in, const float* __restrict__ w,
    float* __restrict__ out,
    int K, int O, size_t in_bstride,
    int mode, float scale,
    const float* __restrict__ res, size_t res_bstride,
    const float* __restrict__ mul, size_t mul_bstride)
{
    __shared__ float wlds[TO * 344];   // rows ob..ob+TO-1 of w, contiguous

    const int b   = blockIdx.z;
    const int ob  = blockIdx.y * TO;
    const int tid = threadIdx.x;
    const int hw4 = blockIdx.x * 256 + tid;

    const int rows  = min(TO, O - ob);
    const int total = rows * K;
    const float* wsrc = w + (size_t)ob * K;
    for (int idx = tid; idx < total; idx += 256) wlds[idx] = wsrc[idx];
    __syncthreads();

    if (hw4 >= HW4) return;

    float4 acc[TO];
#pragma unroll
    for (int j = 0; j < TO; ++j) acc[j] = make_float4(0.f, 0.f, 0.f, 0.f);

    const float* inp = in + (size_t)b * in_bstride + (size_t)hw4 * 4;
#pragma unroll 2
    for (int c = 0; c < K; ++c) {
        float4 xv = *(const float4*)(inp + (size_t)c * HW);
#pragma unroll
        for (int j = 0; j < TO; ++j) {
            float wj = wlds[j * K + c];
            acc[j].x += wj * xv.x;
            acc[j].y += wj * xv.y;
            acc[j].z += wj * xv.z;
            acc[j].w += wj * xv.w;
        }
    }

    for (int j = 0; j < rows; ++j) {
        float4 v = acc[j];
        size_t pix = (size_t)(ob + j) * HW + (size_t)hw4 * 4;
        if (mode == 1) {
            v.x *= scale; v.y *= scale; v.z *= scale; v.w *= scale;
        } else if (mode == 2) {
            float4 r = *(const float4*)(res + (size_t)b * res_bstride + pix);
            v.x = tanhf(v.x) + r.x; v.y = tanhf(v.y) + r.y;
            v.z = tanhf(v.z) + r.z; v.w = tanhf(v.w) + r.w;
        } else if (mode == 3) {
            float4 r = *(const float4*)(res + (size_t)b * res_bstride + pix);
            float4 m = *(const float4*)(mul + (size_t)b * mul_bstride + pix);
            v.x = (tanhf(v.x) + r.x) * m.x; v.y = (tanhf(v.y) + r.y) * m.y;
            v.z = (tanhf(v.z) + r.z) * m.z; v.w = (tanhf(v.w) + r.w) * m.w;
        }
        *(float4*)(out + ((size_t)b * O + ob + j) * HW + (size_t)hw4 * 4) = v;
    }
}

// ---------------------------------------------------------------------------
// 16x16 block mean-pool 112x112 -> 7x7.  grid (C, B), block 64 (49 active).
// ---------------------------------------------------------------------------
__global__ __launch_bounds__(64) void pool_k(
    const float* __restrict__ ctx, float* __restrict__ pooled, int C)
{
    const int c = blockIdx.x, b = blockIdx.y, t = threadIdx.x;
    if (t >= 49) return;
    const int ph = t / 7, pw = t % 7;
    const float* src = ctx + ((size_t)b * C + c) * HW;
    float sum = 0.f;
    for (int i = 0; i < 16; ++i) {
        const float* row = src + (ph * 16 + i) * W_IMG + pw * 16;
        for (int j = 0; j < 16; ++j) sum += row[j];
    }
    pooled[((size_t)b * C + c) * 49 + t] = sum * (1.0f / 256.0f);
}

// ---------------------------------------------------------------------------
// key[b,o,l] = sum_c wk[o,c] * pooled[b,c,l].  grid (O, B), block 64.
// ---------------------------------------------------------------------------
__global__ __launch_bounds__(64) void keygemm_k(
    const float* __restrict__ pooled, const float* __restrict__ wk,
    float* __restrict__ key, int K, int O)
{
    const int o = blockIdx.x, b = blockIdx.y, l = threadIdx.x;
    if (l >= 49) return;
    float s = 0.f;
    for (int c = 0; c < K; ++c)
        s += wk[(size_t)o * K + c] * pooled[((size_t)b * K + c) * 49 + l];
    key[((size_t)b * O + o) * 49 + l] = s;
}

// ---------------------------------------------------------------------------
// Attention scores: per (b,g,hw): s[l] = sum_c q[b,g*hd+c,hw]*key[b,g*hd+c,l];
// e[o] = sum_l s[l]*wp[o,l] + pb[o];  softmax over [0:9] and [9:18] -> attn.
// grid (HW/256=49, 2, B), block 256.
// ---------------------------------------------------------------------------
__global__ __launch_bounds__(256) void attn_k(
    const float* __restrict__ q, const float* __restrict__ key,
    const float* __restrict__ wp, const float* __restrict__ pb,
    float* __restrict__ attn, int hd)
{
    __shared__ float klds[86 * 52];   // padded rows (49 -> 52) for float4 reads
    __shared__ float plds[18 * 52];
    __shared__ float pblds[18];

    const int b = blockIdx.z, g = blockIdx.y, tid = threadIdx.x;

    for (int idx = tid; idx < hd * 49; idx += 256) {
        int c = idx / 49, l = idx - c * 49;
        klds[c * 52 + l] = key[((size_t)(b * 2 + g) * hd + c) * 49 + l];
    }
    for (int idx = tid; idx < hd * 3; idx += 256) {
        int c = idx / 3;
        klds[c * 52 + 49 + (idx - c * 3)] = 0.f;
    }
    for (int idx = tid; idx < 18 * 49; idx += 256) {
        int o = idx / 49, l = idx - o * 49;
        plds[o * 52 + l] = wp[o * 49 + l];
    }
    for (int idx = tid; idx < 18 * 3; idx += 256) {
        int o = idx / 3;
        plds[o * 52 + 49 + (idx - o * 3)] = 0.f;
    }
    if (tid < 18) pblds[tid] = pb[tid];
    __syncthreads();

    const int hw = blockIdx.x * 256 + tid;

    float4 s[13];
#pragma unroll
    for (int t = 0; t < 13; ++t) s[t] = make_float4(0.f, 0.f, 0.f, 0.f);

    const float* qp = q + (size_t)(b * 2 + g) * hd * HW + hw;
    for (int c = 0; c < hd; ++c) {
        float qv = qp[(size_t)c * HW];
        const float4* kr = (const float4*)(klds + c * 52);
#pragma unroll
        for (int t = 0; t < 13; ++t) {
            float4 kv = kr[t];
            s[t].x += qv * kv.x; s[t].y += qv * kv.y;
            s[t].z += qv * kv.z; s[t].w += qv * kv.w;
        }
    }

    float e[18];
#pragma unroll
    for (int o = 0; o < 18; ++o) {
        const float4* pr = (const float4*)(plds + o * 52);
        float4 a = make_float4(0.f, 0.f, 0.f, 0.f);
#pragma unroll
        for (int t = 0; t < 13; ++t) {
            float4 pv = pr[t];
            a.x += s[t].x * pv.x; a.y += s[t].y * pv.y;
            a.z += s[t].z * pv.z; a.w += s[t].w * pv.w;
        }
        e[o] = pblds[o] + a.x + a.y + a.z + a.w;
    }

    float* outp = attn + ((size_t)(b * 2 + g) * HW + hw) * 18;
#pragma unroll
    for (int half = 0; half < 2; ++half) {
        int base = half * 9;
        float m = e[base];
#pragma unroll
        for (int k = 1; k < 9; ++k) m = fmaxf(m, e[base + k]);
        float sum = 0.f, ex[9];
#pragma unroll
        for (int k = 0; k < 9; ++k) { ex[k] = expf(e[base + k] - m); sum += ex[k]; }
        float inv = 1.0f / sum;
#pragma unroll
        for (int k = 0; k < 9; ++k) outp[base + k] = ex[k] * inv;
    }
}

// ---------------------------------------------------------------------------
// Dynamic depthwise 3x3 mix. x channel c (of C total; halves of C_half, heads
// of hd within a half). attn[b,g,hw,18]; first half uses taps 0..8, second 9..17.
// grid (49, C, B), block 256.
// ---------------------------------------------------------------------------
__global__ __launch_bounds__(256) void dyndw_k(
    const float* __restrict__ x, const float* __restrict__ attn,
    float* __restrict__ y, int C, int C_half, int hd, size_t x_bstride)
{
    const int b = blockIdx.z, c = blockIdx.y;
    const int hw = blockIdx.x * 256 + threadIdx.x;
    const int h = hw / W_IMG, w = hw - h * W_IMG;

    const int half = c / C_half;
    const int g = (c - half * C_half) / hd;

    const float* ap = attn + ((size_t)(b * 2 + g) * HW + hw) * 18 + half * 9;
    float a[9];
#pragma unroll
    for (int k = 0; k < 9; ++k) a[k] = ap[k];

    const float* xp = x + (size_t)b * x_bstride + (size_t)c * HW;
    float s = 0.f;
#pragma unroll
    for (int i = 0; i < 3; ++i) {
        int hh = h + i - 1;
#pragma unroll
        for (int j = 0; j < 3; ++j) {
            int ww = w + j - 1;
            float v = (hh >= 0 && hh < 112 && ww >= 0 && ww < 112)
                          ? xp[hh * W_IMG + ww] : 0.f;
            s += v * a[i * 3 + j];
        }
    }
    y[((size_t)b * C + c) * HW + hw] = s;
}

// ---------------------------------------------------------------------------
extern "C" void kernel_launch(void* const* d_in, const int* in_sizes, int n_in,
                              void* d_out, int out_size, void* d_ws, size_t ws_size,
                              hipStream_t stream) {
    const float* x      = (const float*)d_in[0];
    const float* pin_w  = (const float*)d_in[1];
    const float* ctx_w  = (const float*)d_in[2];
    const float* ctx1_w = (const float*)d_in[3];
    const float* ctx2_w = (const float*)d_in[4];
    const float* pout_w = (const float*)d_in[5];
    const float* cm0_q  = (const float*)d_in[6];
    const float* cm0_k  = (const float*)d_in[7];
    const float* cm0_p  = (const float*)d_in[8];
    const float* cm0_pb = (const float*)d_in[9];
    const float* cm0_o  = (const float*)d_in[10];
    const float* cm1_q  = (const float*)d_in[11];
    const float* cm1_k  = (const float*)d_in[12];
    const float* cm1_p  = (const float*)d_in[13];
    const float* cm1_pb = (const float*)d_in[14];
    const float* cm1_o  = (const float*)d_in[15];
    const float* cm2_q  = (const float*)d_in[16];
    const float* cm2_k  = (const float*)d_in[17];
    const float* cm2_p  = (const float*)d_in[18];
    const float* cm2_pb = (const float*)d_in[19];
    const float* cm2_o  = (const float*)d_in[20];
    float* out = (float*)d_out;

    float* ws = (float*)d_ws;
    // ws layout (floats); total ~33.3M floats = 133 MB
    float* x_in  = ws;                         // [2,344,HW]; later x1p(0) + prod(+4315136)
    float* y_buf = ws + 8630272;               // [2,344,HW]; later y1(0), y2(+4315136)
    float* x_dw  = ws + 17260544;              // [2,344,HW]
    float* ctxb  = ws + 25890816;              // [2,86,HW]; later ctx1(0), ctx2(+1078784)
    float* q_buf = ws + 28048384;              // [2,172,HW]; later q1(0), q2(+2157568)
    float* attnb = ws + 32363520;              // [2,2,HW,18]
    float* pooled= ws + 33266688;              // [2,86,49] max
    float* keyb  = ws + 33275116;              // [2,172,49] max

    float* x1p  = x_in;
    float* prod = x_in + 4315136;
    float* ctx1 = ctxb;
    float* ctx2 = ctxb + 1078784;
    float* q2   = q_buf + 2157568;
    float* y2   = y_buf + 4315136;

    const float sc0 = 1.0f / sqrtf(86.0f);
    const float sc1 = 1.0f / sqrtf(43.0f);
    const dim3 cblk(256);
    const size_t BS344 = (size_t)344 * HW, BS172 = (size_t)172 * HW,
                 BS86 = (size_t)86 * HW, BS64 = (size_t)64 * HW,
                 BS43 = (size_t)43 * HW;
    (void)BS86; (void)BS43;

#define CONV(IN, WGT, OUT, K, O, BSTR, MODE, SC, RES, RBSTR, MUL, MBSTR)        \
    conv1x1_k<<<dim3(13, ((O) + TO - 1) / TO, B_SZ), cblk, 0, stream>>>(        \
        IN, WGT, OUT, K, O, BSTR, MODE, SC, RES, RBSTR, MUL, MBSTR)

    // 1. x_in = pin_w @ x
    CONV(x, pin_w, x_in, 64, 344, BS64, 0, 1.f, nullptr, 0, nullptr, 0);
    // 2. ctx_dw = ctx_w @ x_in
    CONV(x_in, ctx_w, ctxb, 344, 86, BS344, 0, 1.f, nullptr, 0, nullptr, 0);
    // 3. q0 = cm0_q @ x_in * scale
    CONV(x_in, cm0_q, q_buf, 344, 172, BS344, 1, sc0, nullptr, 0, nullptr, 0);
    // 4-6. pool, key, attn for cm0
    pool_k<<<dim3(86, B_SZ), dim3(64), 0, stream>>>(ctxb, pooled, 86);
    keygemm_k<<<dim3(172, B_SZ), dim3(64), 0, stream>>>(pooled, cm0_k, keyb, 86, 172);
    attn_k<<<dim3(49, 2, B_SZ), dim3(256), 0, stream>>>(q_buf, keyb, cm0_p, cm0_pb, attnb, 86);
    // 7. dynamic depthwise mix on x_in
    dyndw_k<<<dim3(49, 344, B_SZ), dim3(256), 0, stream>>>(x_in, attnb, y_buf, 344, 172, 86, BS344);
    // 8. x_dw = cm0_o @ y
    CONV(y_buf, cm0_o, x_dw, 344, 344, BS344, 0, 1.f, nullptr, 0, nullptr, 0);

    // 9-10. ctx1/ctx2 from halves of x_dw
    CONV(x_dw, ctx1_w, ctx1, 172, 43, BS344, 0, 1.f, nullptr, 0, nullptr, 0);
    CONV(x_dw + BS172, ctx2_w, ctx2, 172, 43, BS344, 0, 1.f, nullptr, 0, nullptr, 0);

    // ---- contmix1 on x1 ----
    CONV(x_dw, cm1_q, q_buf, 172, 86, BS344, 1, sc1, nullptr, 0, nullptr, 0);
    pool_k<<<dim3(43, B_SZ), dim3(64), 0, stream>>>(ctx1, pooled, 43);
    keygemm_k<<<dim3(86, B_SZ), dim3(64), 0, stream>>>(pooled, cm1_k, keyb, 43, 86);
    attn_k<<<dim3(49, 2, B_SZ), dim3(256), 0, stream>>>(q_buf, keyb, cm1_p, cm1_pb, attnb, 43);
    dyndw_k<<<dim3(49, 172, B_SZ), dim3(256), 0, stream>>>(x_dw, attnb, y_buf, 172, 86, 43, BS344);
    // x1p = tanh(cm1_o @ y1) + x1
    CONV(y_buf, cm1_o, x1p, 172, 172, BS172, 2, 1.f, x_dw, BS344, nullptr, 0);

    // ---- contmix2 on x2 ----
    CONV(x_dw + BS172, cm2_q, q2, 172, 86, BS344, 1, sc1, nullptr, 0, nullptr, 0);
    pool_k<<<dim3(43, B_SZ), dim3(64), 0, stream>>>(ctx2, pooled, 43);
    keygemm_k<<<dim3(86, B_SZ), dim3(64), 0, stream>>>(pooled, cm2_k, keyb, 43, 86);
    attn_k<<<dim3(49, 2, B_SZ), dim3(256), 0, stream>>>(q2, keyb, cm2_p, cm2_pb, attnb, 43);
    dyndw_k<<<dim3(49, 172, B_SZ), dim3(256), 0, stream>>>(x_dw + BS172, attnb, y2, 172, 86, 43, BS344);
    // prod = (tanh(cm2_o @ y2) + x2) * x1p
    CONV(y2, cm2_o, prod, 172, 172, BS172, 3, 1.f, x_dw + BS172, BS344, x1p, BS172);

    // final: out = pout_w @ prod
    CONV(prod, pout_w, out, 172, 64, BS172, 0, 1.f, nullptr, 0, nullptr, 0);
#undef CONV
}

// Round 3
// 764.080 us; speedup vs baseline: 1.3365x; 1.3365x over previous
//
#include <hip/hip_runtime.h>
#include <math.h>

#define HW 12544      // 112*112
#define W_IMG 112
#define B_SZ 2

typedef __attribute__((ext_vector_type(8))) short s8v;   // 8 bf16 (4 VGPRs)
typedef __attribute__((ext_vector_type(4))) float f4v;   // MFMA acc

__device__ __forceinline__ void split_bf16(float x, unsigned short& h, unsigned short& l) {
    unsigned u  = __float_as_uint(x);
    unsigned hb = (u + 0x7FFFu + ((u >> 16) & 1u)) >> 16;
    float hf    = __uint_as_float(hb << 16);
    float r     = x - hf;
    unsigned ur = __float_as_uint(r);
    unsigned lb = (ur + 0x7FFFu + ((ur >> 16) & 1u)) >> 16;
    h = (unsigned short)hb; l = (unsigned short)lb;
}

// ---------------------------------------------------------------------------
// Weight split: fp32 [O][K] -> bf16 hi/lo [Mp][Kp] (zero padded). 11 convs.
// ---------------------------------------------------------------------------
struct WSplitArgs {
    const float* src[11];
    unsigned short* hi[11];
    unsigned short* lo[11];
    int O[11]; int K[11]; int Kp[11]; int MpKp[11];
};

__global__ __launch_bounds__(256) void wsplit_k(WSplitArgs a) {
    const int ci  = blockIdx.y;
    const int idx = blockIdx.x * 256 + threadIdx.x;
    if (idx >= a.MpKp[ci]) return;
    const int Kp = a.Kp[ci];
    const int o = idx / Kp, k = idx - o * Kp;
    float v = 0.f;
    if (o < a.O[ci] && k < a.K[ci]) v = a.src[ci][(size_t)o * a.K[ci] + k];
    unsigned short h, l;
    split_bf16(v, h, l);
    a.hi[ci][idx] = h; a.lo[ci][idx] = l;
}

// ---------------------------------------------------------------------------
// Transpose + split: fp32 [C][HW] (+bstride per batch) -> bf16 hi/lo [HW][Kp]
// (k-contiguous rows, zero-padded c in [C,Kp)). 32x32 LDS tile.
// grid (HW/32=392, Kp/32, B), block 256.
// ---------------------------------------------------------------------------
__global__ __launch_bounds__(256) void tsplit_k(
    const float* __restrict__ src, size_t bstride, int C, int Kp,
    unsigned short* __restrict__ hi, unsigned short* __restrict__ lo)
{
    __shared__ __align__(16) float t[32][36];
    const int b   = blockIdx.z;
    const int hw0 = blockIdx.x * 32;
    const int c0  = blockIdx.y * 32;
    const int tid = threadIdx.x;

    {
        const int cl = tid >> 3, hq = (tid & 7) * 4;
        const int c  = c0 + cl;
        float4 v = make_float4(0.f, 0.f, 0.f, 0.f);
        if (c < C)
            v = *(const float4*)(src + (size_t)b * bstride + (size_t)c * HW + hw0 + hq);
        *(float4*)&t[cl][hq] = v;
    }
    __syncthreads();

    const int hl = tid >> 3, cq = (tid & 7) * 4;
    float v0 = t[cq + 0][hl], v1 = t[cq + 1][hl], v2 = t[cq + 2][hl], v3 = t[cq + 3][hl];
    ushort4 h4, l4;
    split_bf16(v0, h4.x, l4.x);
    split_bf16(v1, h4.y, l4.y);
    split_bf16(v2, h4.z, l4.z);
    split_bf16(v3, h4.w, l4.w);
    const size_t row = (size_t)b * HW + hw0 + hl;
    *(ushort4*)(hi + row * Kp + c0 + cq) = h4;
    *(ushort4*)(lo + row * Kp + c0 + cq) = l4;
}

// ---------------------------------------------------------------------------
// Split-bf16 MFMA GEMM: out[b,o,n] = sum_k W[o,k] * X[k,n], n = hw.
// A = W hi/lo [Mp][Kp]; B = X_t hi/lo [b][HW][Kp] (k contiguous).
// Wave: M=32 (2 mtiles) x N=64 (4 nfrags); block 256 = 4 waves -> N=256.
// 3 MFMAs per (A,B) frag pair: hh + lh + hl  (lo*lo dropped, ~2^-18).
// Epilogue modes: 0 none, 1 *scale, 2 tanh(v)+res, 3 (tanh(v)+res)*mul.
// grid (Mp/32, 49, B), block 256.
// ---------------------------------------------------------------------------
__global__ __launch_bounds__(256) void gemm_k(
    const unsigned short* __restrict__ bt_hi, const unsigned short* __restrict__ bt_lo,
    const unsigned short* __restrict__ w_hi,  const unsigned short* __restrict__ w_lo,
    float* __restrict__ out, int O, int Kp,
    int mode, float scale,
    const float* __restrict__ res, size_t res_bstride,
    const float* __restrict__ mul, size_t mul_bstride)
{
    const int b    = blockIdx.z;
    const int tid  = threadIdx.x;
    const int wv   = tid >> 6, lane = tid & 63;
    const int m16  = lane & 15, quad = lane >> 4;
    const int mbase = blockIdx.x * 32;
    const int nbase = blockIdx.y * 256 + wv * 64;

    const unsigned short* wh0 = w_hi + (size_t)(mbase + m16) * Kp + quad * 8;
    const unsigned short* wl0 = w_lo + (size_t)(mbase + m16) * Kp + quad * 8;
    const unsigned short* wh1 = wh0 + (size_t)16 * Kp;
    const unsigned short* wl1 = wl0 + (size_t)16 * Kp;

    const unsigned short* bh[4];
    const unsigned short* bl[4];
#pragma unroll
    for (int f = 0; f < 4; ++f) {
        size_t roff = ((size_t)b * HW + nbase + f * 16 + m16) * Kp + quad * 8;
        bh[f] = bt_hi + roff; bl[f] = bt_lo + roff;
    }

    f4v acc0[4], acc1[4];
#pragma unroll
    for (int f = 0; f < 4; ++f) {
        acc0[f] = (f4v){0.f, 0.f, 0.f, 0.f};
        acc1[f] = (f4v){0.f, 0.f, 0.f, 0.f};
    }

    for (int ks = 0; ks < Kp; ks += 32) {
        s8v ah0 = *(const s8v*)(wh0 + ks);
        s8v al0 = *(const s8v*)(wl0 + ks);
        s8v ah1 = *(const s8v*)(wh1 + ks);
        s8v al1 = *(const s8v*)(wl1 + ks);
#pragma unroll
        for (int f = 0; f < 4; ++f) {
            s8v bhf = *(const s8v*)(bh[f] + ks);
            s8v blf = *(const s8v*)(bl[f] + ks);
            acc0[f] = __builtin_amdgcn_mfma_f32_16x16x32_bf16(ah0, bhf, acc0[f], 0, 0, 0);
            acc0[f] = __builtin_amdgcn_mfma_f32_16x16x32_bf16(al0, bhf, acc0[f], 0, 0, 0);
            acc0[f] = __builtin_amdgcn_mfma_f32_16x16x32_bf16(ah0, blf, acc0[f], 0, 0, 0);
            acc1[f] = __builtin_amdgcn_mfma_f32_16x16x32_bf16(ah1, bhf, acc1[f], 0, 0, 0);
            acc1[f] = __builtin_amdgcn_mfma_f32_16x16x32_bf16(al1, bhf, acc1[f], 0, 0, 0);
            acc1[f] = __builtin_amdgcn_mfma_f32_16x16x32_bf16(ah1, blf, acc1[f], 0, 0, 0);
        }
    }

#pragma unroll
    for (int mp = 0; mp < 2; ++mp) {
#pragma unroll
        for (int f = 0; f < 4; ++f) {
            const int n = nbase + f * 16 + m16;
#pragma unroll
            for (int r = 0; r < 4; ++r) {
                const int o = mbase + mp * 16 + quad * 4 + r;
                if (o < O) {
                    float v = mp ? acc1[f][r] : acc0[f][r];
                    if (mode == 1) {
                        v *= scale;
                    } else if (mode == 2) {
                        v = tanhf(v) + res[(size_t)b * res_bstride + (size_t)o * HW + n];
                    } else if (mode == 3) {
                        v = (tanhf(v) + res[(size_t)b * res_bstride + (size_t)o * HW + n])
                            * mul[(size_t)b * mul_bstride + (size_t)o * HW + n];
                    }
                    out[((size_t)b * O + o) * HW + n] = v;
                }
            }
        }
    }
}

// ---------------------------------------------------------------------------
// 16x16 block mean-pool 112x112 -> 7x7.  grid (C, B), block 64 (49 active).
// ---------------------------------------------------------------------------
__global__ __launch_bounds__(64) void pool_k(
    const float* __restrict__ ctx, float* __restrict__ pooled, int C)
{
    const int c = blockIdx.x, b = blockIdx.y, t = threadIdx.x;
    if (t >= 49) return;
    const int ph = t / 7, pw = t % 7;
    const float* src = ctx + ((size_t)b * C + c) * HW;
    float sum = 0.f;
    for (int i = 0; i < 16; ++i) {
        const float* row = src + (ph * 16 + i) * W_IMG + pw * 16;
        for (int j = 0; j < 16; ++j) sum += row[j];
    }
    pooled[((size_t)b * C + c) * 49 + t] = sum * (1.0f / 256.0f);
}

// ---------------------------------------------------------------------------
// key[b,o,l] = sum_c wk[o,c] * pooled[b,c,l].  grid (O, B), block 64.
// ---------------------------------------------------------------------------
__global__ __launch_bounds__(64) void keygemm_k(
    const float* __restrict__ pooled, const float* __restrict__ wk,
    float* __restrict__ key, int K, int O)
{
    const int o = blockIdx.x, b = blockIdx.y, l = threadIdx.x;
    if (l >= 49) return;
    float s = 0.f;
    for (int c = 0; c < K; ++c)
        s += wk[(size_t)o * K + c] * pooled[((size_t)b * K + c) * 49 + l];
    key[((size_t)b * O + o) * 49 + l] = s;
}

// ---------------------------------------------------------------------------
// Attention scores + double softmax.  Output layout: attn[b][g][18][HW]
// (tap-major, coalesced both on store here and on load in dyndw).
// grid (49, 2, B), block 256.
// ---------------------------------------------------------------------------
__global__ __launch_bounds__(256) void attn_k(
    const float* __restrict__ q, const float* __restrict__ key,
    const float* __restrict__ wp, const float* __restrict__ pb,
    float* __restrict__ attn, int hd)
{
    __shared__ float klds[86 * 52];
    __shared__ float plds[18 * 52];
    __shared__ float pblds[18];

    const int b = blockIdx.z, g = blockIdx.y, tid = threadIdx.x;

    for (int idx = tid; idx < hd * 49; idx += 256) {
        int c = idx / 49, l = idx - c * 49;
        klds[c * 52 + l] = key[((size_t)(b * 2 + g) * hd + c) * 49 + l];
    }
    for (int idx = tid; idx < hd * 3; idx += 256) {
        int c = idx / 3;
        klds[c * 52 + 49 + (idx - c * 3)] = 0.f;
    }
    for (int idx = tid; idx < 18 * 49; idx += 256) {
        int o = idx / 49, l = idx - o * 49;
        plds[o * 52 + l] = wp[o * 49 + l];
    }
    for (int idx = tid; idx < 18 * 3; idx += 256) {
        int o = idx / 3;
        plds[o * 52 + 49 + (idx - o * 3)] = 0.f;
    }
    if (tid < 18) pblds[tid] = pb[tid];
    __syncthreads();

    const int hw = blockIdx.x * 256 + tid;

    float4 s[13];
#pragma unroll
    for (int t = 0; t < 13; ++t) s[t] = make_float4(0.f, 0.f, 0.f, 0.f);

    const float* qp = q + (size_t)(b * 2 + g) * hd * HW + hw;
    for (int c = 0; c < hd; ++c) {
        float qv = qp[(size_t)c * HW];
        const float4* kr = (const float4*)(klds + c * 52);
#pragma unroll
        for (int t = 0; t < 13; ++t) {
            float4 kv = kr[t];
            s[t].x += qv * kv.x; s[t].y += qv * kv.y;
            s[t].z += qv * kv.z; s[t].w += qv * kv.w;
        }
    }

    float e[18];
#pragma unroll
    for (int o = 0; o < 18; ++o) {
        const float4* pr = (const float4*)(plds + o * 52);
        float4 a = make_float4(0.f, 0.f, 0.f, 0.f);
#pragma unroll
        for (int t = 0; t < 13; ++t) {
            float4 pv = pr[t];
            a.x += s[t].x * pv.x; a.y += s[t].y * pv.y;
            a.z += s[t].z * pv.z; a.w += s[t].w * pv.w;
        }
        e[o] = pblds[o] + a.x + a.y + a.z + a.w;
    }

    float* outp = attn + (size_t)(b * 2 + g) * 18 * HW + hw;
#pragma unroll
    for (int half = 0; half < 2; ++half) {
        int base = half * 9;
        float m = e[base];
#pragma unroll
        for (int k = 1; k < 9; ++k) m = fmaxf(m, e[base + k]);
        float sum = 0.f, ex[9];
#pragma unroll
        for (int k = 0; k < 9; ++k) { ex[k] = expf(e[base + k] - m); sum += ex[k]; }
        float inv = 1.0f / sum;
#pragma unroll
        for (int k = 0; k < 9; ++k) outp[(size_t)(base + k) * HW] = ex[k] * inv;
    }
}

// ---------------------------------------------------------------------------
// Dynamic depthwise 3x3 mix, tap-major attn layout. grid (49, C, B), block 256.
// ---------------------------------------------------------------------------
__global__ __launch_bounds__(256) void dyndw_k(
    const float* __restrict__ x, const float* __restrict__ attn,
    float* __restrict__ y, int C, int C_half, int hd, size_t x_bstride)
{
    const int b = blockIdx.z, c = blockIdx.y;
    const int hw = blockIdx.x * 256 + threadIdx.x;
    const int h = hw / W_IMG, w = hw - h * W_IMG;

    const int half = c / C_half;
    const int g = (c - half * C_half) / hd;

    const float* ap = attn + ((size_t)(b * 2 + g) * 18 + half * 9) * HW + hw;
    float a[9];
#pragma unroll
    for (int k = 0; k < 9; ++k) a[k] = ap[(size_t)k * HW];

    const float* xp = x + (size_t)b * x_bstride + (size_t)c * HW;
    float s = 0.f;
#pragma unroll
    for (int i = 0; i < 3; ++i) {
        int hh = h + i - 1;
#pragma unroll
        for (int j = 0; j < 3; ++j) {
            int ww = w + j - 1;
            float v = (hh >= 0 && hh < 112 && ww >= 0 && ww < 112)
                          ? xp[hh * W_IMG + ww] : 0.f;
            s += v * a[i * 3 + j];
        }
    }
    y[((size_t)b * C + c) * HW + hw] = s;
}

// ---------------------------------------------------------------------------
extern "C" void kernel_launch(void* const* d_in, const int* in_sizes, int n_in,
                              void* d_out, int out_size, void* d_ws, size_t ws_size,
                              hipStream_t stream) {
    const float* x      = (const float*)d_in[0];
    const float* pin_w  = (const float*)d_in[1];
    const float* ctx_w  = (const float*)d_in[2];
    const float* ctx1_w = (const float*)d_in[3];
    const float* ctx2_w = (const float*)d_in[4];
    const float* pout_w = (const float*)d_in[5];
    const float* cm0_q  = (const float*)d_in[6];
    const float* cm0_k  = (const float*)d_in[7];
    const float* cm0_p  = (const float*)d_in[8];
    const float* cm0_pb = (const float*)d_in[9];
    const float* cm0_o  = (const float*)d_in[10];
    const float* cm1_q  = (const float*)d_in[11];
    const float* cm1_k  = (const float*)d_in[12];
    const float* cm1_p  = (const float*)d_in[13];
    const float* cm1_pb = (const float*)d_in[14];
    const float* cm1_o  = (const float*)d_in[15];
    const float* cm2_q  = (const float*)d_in[16];
    const float* cm2_k  = (const float*)d_in[17];
    const float* cm2_p  = (const float*)d_in[18];
    const float* cm2_pb = (const float*)d_in[19];
    const float* cm2_o  = (const float*)d_in[20];
    float* out = (float*)d_out;

    float* ws = (float*)d_ws;
    // ---- fp32 region (floats) ----
    float* x_in  = ws;                          // [2,344,HW]
    float* x1p   = ws;                          // [2,172,HW] (after x_in dead)
    float* prod  = ws + 4315136;                // [2,172,HW]
    float* y0    = ws + 8630272;                // [2,344,HW]
    float* y1    = ws + 8630272;                // [2,172,HW]
    float* y2    = ws + 12945408;               // [2,172,HW]
    float* x_dw  = ws + 17260544;               // [2,344,HW]
    float* ctxb  = ws + 25890816;               // [2,86,HW]
    float* ctx1  = ws + 28048384;               // [2,43,HW]
    float* ctx2  = ws + 29127168;               // [2,43,HW]
    float* q0    = ws + 30205952;               // [2,172,HW]
    float* q1    = ws + 30205952;               // [2,86,HW] (after q0 dead)
    float* q2    = ws + 32363520;               // [2,86,HW]
    float* attnb = ws + 34521088;               // [2,2,18,HW]
    float* pooled= ws + 35424256;               // [2,86,49]
    float* keyb  = ws + 35432704;               // [2,172,49]
    // ---- bf16 region (ushorts) ----
    unsigned short* ub = (unsigned short*)(ws + 35449568);
    // weight splits [0 .. 790528)
    static const int   WOFF[11] = {0, 45056, 112640, 247808, 495616, 520192,
                                   544768, 581632, 618496, 692224, 765952};
    static const int   WO[11]  = {344, 86, 172, 344, 43, 43, 86, 86, 172, 172, 64};
    static const int   WK[11]  = {64, 344, 344, 344, 172, 172, 172, 172, 172, 172, 172};
    static const int   WKP[11] = {64, 352, 352, 352, 192, 192, 192, 192, 192, 192, 192};
    static const int   WMP[11] = {352, 96, 192, 352, 64, 64, 96, 96, 192, 192, 64};
    // X_t planes
    unsigned short* xt_hi    = ub + 790528;     // [2,HW,64]
    unsigned short* xt_lo    = ub + 2396160;
    unsigned short* xint_hi  = ub + 4001792;    // [2,HW,352] (pool A)
    unsigned short* xint_lo  = ub + 12832768;
    unsigned short* x1t_hi   = ub + 4001792;    // [2,HW,192] (pool A reuse)
    unsigned short* x1t_lo   = ub + 8818688;
    unsigned short* x2t_hi   = ub + 13635584;
    unsigned short* x2t_lo   = ub + 18452480;
    unsigned short* yt_hi    = ub + 23269376;   // [2,HW,352] (pool B)
    unsigned short* yt_lo    = ub + 32100352;
    unsigned short* y1t_hi   = ub + 23269376;   // [2,HW,192] (pool B reuse)
    unsigned short* y1t_lo   = ub + 28086272;
    unsigned short* y2t_hi   = ub + 32903168;
    unsigned short* y2t_lo   = ub + 37720064;
    unsigned short* pt_hi    = ub + 42536960;   // [2,HW,192]
    unsigned short* pt_lo    = ub + 47353856;

    const float sc0 = 1.0f / sqrtf(86.0f);
    const float sc1 = 1.0f / sqrtf(43.0f);
    const size_t BS344 = (size_t)344 * HW, BS172 = (size_t)172 * HW, BS64 = (size_t)64 * HW;

    // ---- 0. split all weights ----
    WSplitArgs wa;
    const float* wsrc[11] = {pin_w, ctx_w, cm0_q, cm0_o, ctx1_w, ctx2_w,
                             cm1_q, cm2_q, cm1_o, cm2_o, pout_w};
    for (int i = 0; i < 11; ++i) {
        wa.src[i] = wsrc[i];
        wa.hi[i]  = ub + WOFF[i];
        wa.lo[i]  = ub + WOFF[i] + WMP[i] * WKP[i];
        wa.O[i] = WO[i]; wa.K[i] = WK[i]; wa.Kp[i] = WKP[i];
        wa.MpKp[i] = WMP[i] * WKP[i];
    }
    wsplit_k<<<dim3(484, 11), 256, 0, stream>>>(wa);

#define TSPLIT(SRC, BSTR, C, KP, HI, LO)                                        \
    tsplit_k<<<dim3(392, (KP) / 32, B_SZ), 256, 0, stream>>>(SRC, BSTR, C, KP, HI, LO)
#define GEMM(CI, BH, BL, OUT, MODE, SC, RES, RB, MUL, MB)                       \
    gemm_k<<<dim3(WMP[CI] / 32, 49, B_SZ), 256, 0, stream>>>(                   \
        BH, BL, ub + WOFF[CI], ub + WOFF[CI] + WMP[CI] * WKP[CI],               \
        OUT, WO[CI], WKP[CI], MODE, SC, RES, RB, MUL, MB)

    // ---- pin: x_in = pin_w @ x ----
    TSPLIT(x, BS64, 64, 64, xt_hi, xt_lo);
    GEMM(0, xt_hi, xt_lo, x_in, 0, 1.f, nullptr, 0, nullptr, 0);
    TSPLIT(x_in, BS344, 344, 352, xint_hi, xint_lo);

    // ---- contmix0 ----
    GEMM(1, xint_hi, xint_lo, ctxb, 0, 1.f, nullptr, 0, nullptr, 0);   // ctx_dw
    GEMM(2, xint_hi, xint_lo, q0, 1, sc0, nullptr, 0, nullptr, 0);     // q0
    pool_k<<<dim3(86, B_SZ), dim3(64), 0, stream>>>(ctxb, pooled, 86);
    keygemm_k<<<dim3(172, B_SZ), dim3(64), 0, stream>>>(pooled, cm0_k, keyb, 86, 172);
    attn_k<<<dim3(49, 2, B_SZ), dim3(256), 0, stream>>>(q0, keyb, cm0_p, cm0_pb, attnb, 86);
    dyndw_k<<<dim3(49, 344, B_SZ), dim3(256), 0, stream>>>(x_in, attnb, y0, 344, 172, 86, BS344);
    TSPLIT(y0, BS344, 344, 352, yt_hi, yt_lo);
    GEMM(3, yt_hi, yt_lo, x_dw, 0, 1.f, nullptr, 0, nullptr, 0);       // x_dw

    // ---- transpose halves of x_dw ----
    TSPLIT(x_dw, BS344, 172, 192, x1t_hi, x1t_lo);
    TSPLIT(x_dw + BS172, BS344, 172, 192, x2t_hi, x2t_lo);

    // ---- contmix1 on x1 ----
    GEMM(4, x1t_hi, x1t_lo, ctx1, 0, 1.f, nullptr, 0, nullptr, 0);
    GEMM(6, x1t_hi, x1t_lo, q1, 1, sc1, nullptr, 0, nullptr, 0);
    pool_k<<<dim3(43, B_SZ), dim3(64), 0, stream>>>(ctx1, pooled, 43);
    keygemm_k<<<dim3(86, B_SZ), dim3(64), 0, stream>>>(pooled, cm1_k, keyb, 43, 86);
    attn_k<<<dim3(49, 2, B_SZ), dim3(256), 0, stream>>>(q1, keyb, cm1_p, cm1_pb, attnb, 43);
    dyndw_k<<<dim3(49, 172, B_SZ), dim3(256), 0, stream>>>(x_dw, attnb, y1, 172, 86, 43, BS344);
    TSPLIT(y1, BS172, 172, 192, y1t_hi, y1t_lo);
    GEMM(8, y1t_hi, y1t_lo, x1p, 2, 1.f, x_dw, BS344, nullptr, 0);     // x1p

    // ---- contmix2 on x2 ----
    GEMM(5, x2t_hi, x2t_lo, ctx2, 0, 1.f, nullptr, 0, nullptr, 0);
    GEMM(7, x2t_hi, x2t_lo, q2, 1, sc1, nullptr, 0, nullptr, 0);
    pool_k<<<dim3(43, B_SZ), dim3(64), 0, stream>>>(ctx2, pooled, 43);
    keygemm_k<<<dim3(86, B_SZ), dim3(64), 0, stream>>>(pooled, cm2_k, keyb, 43, 86);
    attn_k<<<dim3(49, 2, B_SZ), dim3(256), 0, stream>>>(q2, keyb, cm2_p, cm2_pb, attnb, 43);
    dyndw_k<<<dim3(49, 172, B_SZ), dim3(256), 0, stream>>>(x_dw + BS172, attnb, y2, 172, 86, 43, BS344);
    TSPLIT(y2, BS172, 172, 192, y2t_hi, y2t_lo);
    GEMM(9, y2t_hi, y2t_lo, prod, 3, 1.f, x_dw + BS172, BS344, x1p, BS172); // prod

    // ---- pout ----
    TSPLIT(prod, BS172, 172, 192, pt_hi, pt_lo);
    GEMM(10, pt_hi, pt_lo, out, 0, 1.f, nullptr, 0, nullptr, 0);

#undef TSPLIT
#undef GEMM
}